// Round 22
// baseline (115.373 us; speedup 1.0000x reference)
//
#include <hip/hip_runtime.h>

#define EMB 64
#define CHUNK 512

#if defined(__has_builtin)
#if __has_builtin(__builtin_amdgcn_sdot4)
#define USE_SDOT 1
#endif
#endif
#ifndef USE_SDOT
#define USE_SDOT 0
#endif

// ---------- fused prep: segment boundaries | q4 conversion ----------
__global__ __launch_bounds__(256) void prep_kernel(
    const int* __restrict__ seg, int* __restrict__ row_start, int T, int B,
    const float* __restrict__ src, uint* __restrict__ dst,
    float* __restrict__ scales, int nrows, int segBlocks) {
    if ((int)blockIdx.x < segBlocks) {
        const int t = (int)blockIdx.x * (int)blockDim.x + (int)threadIdx.x;
        if (t >= T) return;
        const int s  = seg[t];
        const int sp = (t == 0) ? -1 : seg[t - 1];
        for (int b = sp + 1; b <= s; ++b) row_start[b] = t;
        if (t == T - 1) {
            for (int b = s + 1; b <= B; ++b) row_start[b] = T;
        }
    } else {
        // f32 -> signed int4 stored excess-8: value = s*q', q' in [-7,7], nib = q'+8
        const int wave = (int)(((size_t)((int)blockIdx.x - segBlocks) * blockDim.x + threadIdx.x) >> 6);
        const int lane = (int)threadIdx.x & 63;
        const int g = lane >> 3, sub = lane & 7;
        const int r = wave * 8 + g;
        if (r >= nrows) return;

        const float* p = src + (size_t)r * EMB + (sub << 3);
        float e[8];
        #pragma unroll
        for (int k = 0; k < 8; ++k) e[k] = p[k];
        float mx = 0.f;
        #pragma unroll
        for (int k = 0; k < 8; ++k) mx = fmaxf(mx, fabsf(e[k]));
        mx = fmaxf(mx, __shfl_xor(mx, 1, 64));
        mx = fmaxf(mx, __shfl_xor(mx, 2, 64));
        mx = fmaxf(mx, __shfl_xor(mx, 4, 64));

        const float scale = mx * (1.0f / 7.0f);
        const float inv   = (mx > 0.f) ? (7.0f / mx) : 0.f;

        uint w = 0;
        #pragma unroll
        for (int k = 0; k < 8; ++k) {
            int q = (int)rintf(e[k] * inv);
            q = q < -7 ? -7 : (q > 7 ? 7 : q);
            w |= ((uint)(q + 8)) << (4 * k);
        }
        dst[(size_t)r * 8 + sub] = w;
        if (sub == 0) scales[r] = scale;
    }
}

// ---------- Kernel B v16: block-scope LDS id staging (barrier-correct) ----
// Block = 4 waves x (8 groups x 8 lanes); group owns row bb0 + wave*8 + g;
// lane sub covers dims [8*sub..8*sub+7] (one q4 dword). The block's 32 rows
// occupy ONE contiguous flat range [row_start[bb0], row_start[bb0+32]) ->
// staged chunk-wise into shared LDS by all 256 threads with __syncthreads()
// after staging and before overwrite (chunk loop is block-uniform, so the
// barriers are legal). Fixes R18's flaky same-wave no-barrier race.
__global__ __launch_bounds__(256) void svdpp_main_q4(
    const int*   __restrict__ scientist_ids,
    const int*   __restrict__ paper_ids,
    const int*   __restrict__ flat_papers,
    const int*   __restrict__ row_start,
    const float* __restrict__ scientist_factors,
    const float* __restrict__ paper_factors,
    const uint*  __restrict__ imp_q4,
    const float* __restrict__ imp_scale,
    const float* __restrict__ scientist_bias,
    const float* __restrict__ paper_bias,
    float*       __restrict__ out,
    int B) {
    const int tid  = (int)threadIdx.x;
    const int lane = tid & 63;
    const int wv   = tid >> 6;         // wave in block, 0..3
    const int g    = lane >> 3;
    const int sub  = lane & 7;
    const int bb0  = (int)blockIdx.x * 32;     // block's first row (uniform)
    const int myrow = bb0 + wv * 8 + g;
    const bool valid = myrow < B;
    const int b = valid ? myrow : (B - 1);

    __shared__ int lds_ids[CHUNK];

    // block-uniform flat range (scalar loads, L1/L2-hot)
    int ehi = bb0 + 32; if (ehi > B) ehi = B;
    const int S_blk = row_start[bb0];
    const int E_blk = row_start[ehi];

    const int sid   = __builtin_nontemporal_load(scientist_ids + b);
    const int pid   = __builtin_nontemporal_load(paper_ids + b);
    const int start = row_start[b];
    const int end   = row_start[b + 1];

    // paper row (hot table): 2 cached float4 loads
    const float4* pf = reinterpret_cast<const float4*>(
        paper_factors + ((size_t)pid << 6)) + 2 * sub;
    const float4 pe0 = pf[0];
    const float4 pe1 = pf[1];

    // scientist row (zero-reuse): scalar nt loads
    const float* sf = scientist_factors + ((size_t)sid << 6) + (sub << 3);
    float se[8];
    #pragma unroll
    for (int k = 0; k < 8; ++k) se[k] = __builtin_nontemporal_load(sf + k);

    const float sb = __builtin_nontemporal_load(scientist_bias + sid);
    const float pb = __builtin_nontemporal_load(paper_bias + pid);

    const float base = se[0]*pe0.x + se[1]*pe0.y + se[2]*pe0.z + se[3]*pe0.w
                     + se[4]*pe1.x + se[5]*pe1.y + se[6]*pe1.z + se[7]*pe1.w;

#if USE_SDOT
    float pmax = fmaxf(fmaxf(fmaxf(fabsf(pe0.x), fabsf(pe0.y)),
                             fmaxf(fabsf(pe0.z), fabsf(pe0.w))),
                       fmaxf(fmaxf(fabsf(pe1.x), fabsf(pe1.y)),
                             fmaxf(fabsf(pe1.z), fabsf(pe1.w))));
    const float sp   = pmax * (1.0f / 127.0f);
    const float pinv = (pmax > 0.f) ? (127.0f / pmax) : 0.f;
    int qp[8];
    qp[0] = (int)rintf(pe0.x * pinv); qp[1] = (int)rintf(pe0.y * pinv);
    qp[2] = (int)rintf(pe0.z * pinv); qp[3] = (int)rintf(pe0.w * pinv);
    qp[4] = (int)rintf(pe1.x * pinv); qp[5] = (int)rintf(pe1.y * pinv);
    qp[6] = (int)rintf(pe1.z * pinv); qp[7] = (int)rintf(pe1.w * pinv);
    const int plo = (qp[0] & 0xff) | ((qp[2] & 0xff) << 8)
                  | ((qp[4] & 0xff) << 16) | ((qp[6] & 0xff) << 24);
    const int phi = (qp[1] & 0xff) | ((qp[3] & 0xff) << 8)
                  | ((qp[5] & 0xff) << 16) | ((qp[7] & 0xff) << 24);
    const int m8psum = -8 * (qp[0] + qp[1] + qp[2] + qp[3]
                           + qp[4] + qp[5] + qp[6] + qp[7]);
    const uint M = 0x0F0F0F0Fu;

    float A0 = 0.f, A1 = 0.f, A2 = 0.f, A3 = 0.f;
    for (int clo = S_blk; clo < E_blk; clo += CHUNK) {
        const int chi = (clo + CHUNK < E_blk) ? (clo + CHUNK) : E_blk;
        // stage ids: all 256 threads, coalesced (block-uniform loop bounds)
        for (int k = tid; k < chi - clo; k += 256) {
            lds_ids[k] = flat_papers[clo + k];
        }
        __syncthreads();
        int ge = (start > clo) ? start : clo;
        const int gend = (end < chi) ? end : chi;
        for (; ge + 4 <= gend; ge += 4) {
            const int li = ge - clo;
            const int p0 = lds_ids[li];
            const int p1 = lds_ids[li + 1];
            const int p2 = lds_ids[li + 2];
            const int p3 = lds_ids[li + 3];
            const uint u0 = imp_q4[((size_t)p0 << 3) + sub];
            const uint u1 = imp_q4[((size_t)p1 << 3) + sub];
            const uint u2 = imp_q4[((size_t)p2 << 3) + sub];
            const uint u3 = imp_q4[((size_t)p3 << 3) + sub];
            const float s0 = imp_scale[p0];
            const float s1 = imp_scale[p1];
            const float s2 = imp_scale[p2];
            const float s3 = imp_scale[p3];
            const int d0 = __builtin_amdgcn_sdot4((int)(u0 & M), plo,
                           __builtin_amdgcn_sdot4((int)((u0 >> 4) & M), phi, m8psum, false), false);
            const int d1 = __builtin_amdgcn_sdot4((int)(u1 & M), plo,
                           __builtin_amdgcn_sdot4((int)((u1 >> 4) & M), phi, m8psum, false), false);
            const int d2 = __builtin_amdgcn_sdot4((int)(u2 & M), plo,
                           __builtin_amdgcn_sdot4((int)((u2 >> 4) & M), phi, m8psum, false), false);
            const int d3 = __builtin_amdgcn_sdot4((int)(u3 & M), plo,
                           __builtin_amdgcn_sdot4((int)((u3 >> 4) & M), phi, m8psum, false), false);
            A0 = fmaf(s0, (float)d0, A0);
            A1 = fmaf(s1, (float)d1, A1);
            A2 = fmaf(s2, (float)d2, A2);
            A3 = fmaf(s3, (float)d3, A3);
        }
        for (; ge < gend; ++ge) {
            const int p = lds_ids[ge - clo];
            const uint u = imp_q4[((size_t)p << 3) + sub];
            const float s = imp_scale[p];
            const int d = __builtin_amdgcn_sdot4((int)(u & M), plo,
                          __builtin_amdgcn_sdot4((int)((u >> 4) & M), phi, m8psum, false), false);
            A0 = fmaf(s, (float)d, A0);
        }
        __syncthreads();   // protect lds_ids from next chunk's overwrite
    }
    const float acc = sp * ((A0 + A1) + (A2 + A3));
#else
    const float pesum = pe0.x + pe0.y + pe0.z + pe0.w
                      + pe1.x + pe1.y + pe1.z + pe1.w;
    float A0 = 0.f, S0 = 0.f;
    for (int clo = S_blk; clo < E_blk; clo += CHUNK) {
        const int chi = (clo + CHUNK < E_blk) ? (clo + CHUNK) : E_blk;
        for (int k = tid; k < chi - clo; k += 256) {
            lds_ids[k] = flat_papers[clo + k];
        }
        __syncthreads();
        int ge = (start > clo) ? start : clo;
        const int gend = (end < chi) ? end : chi;
        for (; ge < gend; ++ge) {
            const int p = lds_ids[ge - clo];
            const uint u = imp_q4[((size_t)p << 3) + sub];
            const float s = imp_scale[p];
            const uint lo = u & 0x0F0F0F0Fu, hi = (u >> 4) & 0x0F0F0F0Fu;
            const float d = (float)(lo & 0xffu)*pe0.x + (float)(hi & 0xffu)*pe0.y
                          + (float)((lo >> 8) & 0xffu)*pe0.z + (float)((hi >> 8) & 0xffu)*pe0.w
                          + (float)((lo >> 16) & 0xffu)*pe1.x + (float)((hi >> 16) & 0xffu)*pe1.y
                          + (float)(lo >> 24)*pe1.z + (float)(hi >> 24)*pe1.w;
            A0 = fmaf(s, d, A0);  S0 += s;
        }
        __syncthreads();
    }
    const float acc = A0 - 8.0f * S0 * pesum;
#endif

    const int n = end - start;
    const float scale = (n > 0) ? rsqrtf((float)n) : 0.0f;
    float v = base + scale * acc;

    // reduce within the 8-lane group
    v += __shfl_xor(v, 1, 64);
    v += __shfl_xor(v, 2, 64);
    v += __shfl_xor(v, 4, 64);

    if (sub == 0 && valid) {
        __builtin_nontemporal_store(v + sb + pb + 3.82f, out + myrow);
    }
}

// ---------- f32 fallback (ws too small) ----------
__global__ __launch_bounds__(256) void svdpp_main_f32(
    const int*   __restrict__ scientist_ids,
    const int*   __restrict__ paper_ids,
    const int*   __restrict__ flat_papers,
    const int*   __restrict__ row_start,
    const float* __restrict__ scientist_factors,
    const float* __restrict__ paper_factors,
    const float* __restrict__ implicit_factors,
    const float* __restrict__ scientist_bias,
    const float* __restrict__ paper_bias,
    float*       __restrict__ out,
    int B) {
    const int wave = (int)((blockIdx.x * blockDim.x + threadIdx.x) >> 6);
    const int lane = threadIdx.x & 63;
    if (wave >= B) return;
    const int b   = wave;
    const int g   = lane >> 4;
    const int sub = lane & 15;

    const int start = row_start[b];
    const int end   = row_start[b + 1];
    const int n     = end - start;

    float4 accA = make_float4(0.f,0.f,0.f,0.f);
    int i = start;
    for (; i < end; i += 4) {
        const int e = i + g;
        if (e < end) {
            const int p = flat_papers[e];
            const float4 r = *reinterpret_cast<const float4*>(
                implicit_factors + ((size_t)p << 6) + (sub << 2));
            accA.x += r.x; accA.y += r.y; accA.z += r.z; accA.w += r.w;
        }
    }

    const float scale = (n > 0) ? rsqrtf((float)n) : 0.0f;
    const int sid = scientist_ids[b];
    const int pid = paper_ids[b];
    const float4 se = *reinterpret_cast<const float4*>(
        scientist_factors + ((size_t)sid << 6) + (sub << 2));
    const float4 pe = *reinterpret_cast<const float4*>(
        paper_factors + ((size_t)pid << 6) + (sub << 2));

    const float basedot = se.x*pe.x + se.y*pe.y + se.z*pe.z + se.w*pe.w;
    const float tdot    = accA.x*pe.x + accA.y*pe.y + accA.z*pe.z + accA.w*pe.w;
    float v = scale * tdot + ((g == 0) ? basedot : 0.0f);

    #pragma unroll
    for (int off = 1; off < 64; off <<= 1) v += __shfl_xor(v, off, 64);

    if (lane == 0) {
        out[b] = v + scientist_bias[sid] + paper_bias[pid] + 3.82f;
    }
}

extern "C" void kernel_launch(void* const* d_in, const int* in_sizes, int n_in,
                              void* d_out, int out_size, void* d_ws, size_t ws_size,
                              hipStream_t stream) {
    const int* scientist_ids       = (const int*)d_in[0];
    const int* paper_ids           = (const int*)d_in[1];
    const int* flat_papers         = (const int*)d_in[2];
    const int* segment_ids         = (const int*)d_in[3];
    const float* scientist_factors = (const float*)d_in[4];
    const float* paper_factors     = (const float*)d_in[5];
    const float* implicit_factors  = (const float*)d_in[6];
    const float* scientist_bias    = (const float*)d_in[7];
    const float* paper_bias        = (const float*)d_in[8];
    float* out = (float*)d_out;

    const int B      = in_sizes[0];
    const int T      = in_sizes[2];
    const int IMP_N  = in_sizes[6];          // NUM_PAPERS * EMB
    const int NROWS  = IMP_N / EMB;          // NUM_PAPERS

    auto align64 = [](size_t x) { return (x + 63) & ~(size_t)63; };
    size_t off0 = 0;                                   // row_start (B+1 ints)
    size_t off1 = align64(off0 + (size_t)(B + 1) * 4); // imp_q4  (NROWS*32B)
    size_t off2 = align64(off1 + (size_t)NROWS * 32);  // imp_scale (NROWS*4B)
    const size_t need = off2 + (size_t)NROWS * 4;

    int*   row_start  = (int*)((char*)d_ws + off0);
    uint*  imp_q4     = (uint*)((char*)d_ws + off1);
    float* imp_scale  = (float*)((char*)d_ws + off2);

    if (ws_size >= need) {
        {
            const int threads   = 256;
            const int segBlocks = (T + threads - 1) / threads;
            const int cvtBlocks = (NROWS + 31) / 32;   // 8 rows per wave
            prep_kernel<<<segBlocks + cvtBlocks, threads, 0, stream>>>(
                segment_ids, row_start, T, B,
                implicit_factors, imp_q4, imp_scale, NROWS, segBlocks);
        }
        {
            const int threads = 256;                   // 32 output rows per block
            const int blocks  = (B + 31) / 32;
            svdpp_main_q4<<<blocks, threads, 0, stream>>>(
                scientist_ids, paper_ids, flat_papers, row_start,
                scientist_factors, paper_factors, imp_q4, imp_scale,
                scientist_bias, paper_bias, out, B);
        }
    } else {
        {
            const int threads = 256;
            const int blocks  = (T + threads - 1) / threads;
            prep_kernel<<<blocks, threads, 0, stream>>>(
                segment_ids, row_start, T, B,
                implicit_factors, (uint*)nullptr, (float*)nullptr, 0, blocks);
        }
        const int threads = 256;
        const int blocks  = (B + 3) / 4;
        svdpp_main_f32<<<blocks, threads, 0, stream>>>(
            scientist_ids, paper_ids, flat_papers, row_start,
            scientist_factors, paper_factors, implicit_factors,
            scientist_bias, paper_bias, out, B);
    }
}

// Round 23
// 104.606 us; speedup vs baseline: 1.1029x; 1.1029x over previous
//
#include <hip/hip_runtime.h>

#define EMB 64
#define CHUNK 256

#if defined(__has_builtin)
#if __has_builtin(__builtin_amdgcn_sdot4)
#define USE_SDOT 1
#endif
#endif
#ifndef USE_SDOT
#define USE_SDOT 0
#endif

// ---------- fused prep: segment boundaries | q4 conversion ----------
__global__ __launch_bounds__(256) void prep_kernel(
    const int* __restrict__ seg, int* __restrict__ row_start, int T, int B,
    const float* __restrict__ src, uint* __restrict__ dst,
    float* __restrict__ scales, int nrows, int segBlocks) {
    if ((int)blockIdx.x < segBlocks) {
        const int t = (int)blockIdx.x * (int)blockDim.x + (int)threadIdx.x;
        if (t >= T) return;
        const int s  = seg[t];
        const int sp = (t == 0) ? -1 : seg[t - 1];
        for (int b = sp + 1; b <= s; ++b) row_start[b] = t;
        if (t == T - 1) {
            for (int b = s + 1; b <= B; ++b) row_start[b] = T;
        }
    } else {
        // f32 -> signed int4 stored excess-8: value = s*q', q' in [-7,7], nib = q'+8
        const int wave = (int)(((size_t)((int)blockIdx.x - segBlocks) * blockDim.x + threadIdx.x) >> 6);
        const int lane = (int)threadIdx.x & 63;
        const int g = lane >> 3, sub = lane & 7;
        const int r = wave * 8 + g;
        if (r >= nrows) return;

        const float* p = src + (size_t)r * EMB + (sub << 3);
        float e[8];
        #pragma unroll
        for (int k = 0; k < 8; ++k) e[k] = p[k];
        float mx = 0.f;
        #pragma unroll
        for (int k = 0; k < 8; ++k) mx = fmaxf(mx, fabsf(e[k]));
        mx = fmaxf(mx, __shfl_xor(mx, 1, 64));
        mx = fmaxf(mx, __shfl_xor(mx, 2, 64));
        mx = fmaxf(mx, __shfl_xor(mx, 4, 64));

        const float scale = mx * (1.0f / 7.0f);
        const float inv   = (mx > 0.f) ? (7.0f / mx) : 0.f;

        uint w = 0;
        #pragma unroll
        for (int k = 0; k < 8; ++k) {
            int q = (int)rintf(e[k] * inv);
            q = q < -7 ? -7 : (q > 7 ? 7 : q);
            w |= ((uint)(q + 8)) << (4 * k);
        }
        dst[(size_t)r * 8 + sub] = w;
        if (sub == 0) scales[r] = scale;
    }
}

// ---------- Kernel B v17: per-wave LDS id staging + explicit fences -------
// Wave = 8 groups x 8 lanes; group g owns row wave*8+g; lane sub covers dims
// [8*sub..8*sub+7]. Per-wave lds_ids buffer (no block barriers). The same-
// wave ds_write -> ds_read ordering is HW-in-order per wave; the R21 flake
// was COMPILER reordering (reads hoisted above writes, rule-#18 class).
// Fences: s_waitcnt lgkmcnt(0)+sched_barrier(0) after staging; memory-
// clobber + sched_barrier(0) before the next chunk's overwrite.
__global__ __launch_bounds__(256) void svdpp_main_q4(
    const int*   __restrict__ scientist_ids,
    const int*   __restrict__ paper_ids,
    const int*   __restrict__ flat_papers,
    const int*   __restrict__ row_start,
    const float* __restrict__ scientist_factors,
    const float* __restrict__ paper_factors,
    const uint*  __restrict__ imp_q4,
    const float* __restrict__ imp_scale,
    const float* __restrict__ scientist_bias,
    const float* __restrict__ paper_bias,
    float*       __restrict__ out,
    int B) {
    const int wave = (int)((blockIdx.x * blockDim.x + threadIdx.x) >> 6);
    const int lane = threadIdx.x & 63;
    const int g    = lane >> 3;
    const int sub  = lane & 7;
    const int b0   = wave * 8;
    if (b0 >= B) return;
    const bool valid = (b0 + g) < B;
    const int b = valid ? (b0 + g) : (B - 1);
    const int w = (int)(threadIdx.x >> 6);

    __shared__ int lds_ids[4][CHUNK];

    const int sid   = __builtin_nontemporal_load(scientist_ids + b);
    const int pid   = __builtin_nontemporal_load(paper_ids + b);
    const int start = row_start[b];
    const int end   = row_start[b + 1];

    // wave-wide contiguous flat range (shfl at full convergence: safe)
    const int S = __shfl(start, 0, 64);     // row_start[b0]
    const int E = __shfl(end, 63, 64);      // row_start[min(b0+8,B)]

    // paper row (hot table): 2 cached float4 loads
    const float4* pf = reinterpret_cast<const float4*>(
        paper_factors + ((size_t)pid << 6)) + 2 * sub;
    const float4 pe0 = pf[0];
    const float4 pe1 = pf[1];

    // scientist row (zero-reuse): scalar nt loads
    const float* sf = scientist_factors + ((size_t)sid << 6) + (sub << 3);
    float se[8];
    #pragma unroll
    for (int k = 0; k < 8; ++k) se[k] = __builtin_nontemporal_load(sf + k);

    const float sb = __builtin_nontemporal_load(scientist_bias + sid);
    const float pb = __builtin_nontemporal_load(paper_bias + pid);

    const float base = se[0]*pe0.x + se[1]*pe0.y + se[2]*pe0.z + se[3]*pe0.w
                     + se[4]*pe1.x + se[5]*pe1.y + se[6]*pe1.z + se[7]*pe1.w;

#if USE_SDOT
    float pmax = fmaxf(fmaxf(fmaxf(fabsf(pe0.x), fabsf(pe0.y)),
                             fmaxf(fabsf(pe0.z), fabsf(pe0.w))),
                       fmaxf(fmaxf(fabsf(pe1.x), fabsf(pe1.y)),
                             fmaxf(fabsf(pe1.z), fabsf(pe1.w))));
    const float sp   = pmax * (1.0f / 127.0f);
    const float pinv = (pmax > 0.f) ? (127.0f / pmax) : 0.f;
    int qp[8];
    qp[0] = (int)rintf(pe0.x * pinv); qp[1] = (int)rintf(pe0.y * pinv);
    qp[2] = (int)rintf(pe0.z * pinv); qp[3] = (int)rintf(pe0.w * pinv);
    qp[4] = (int)rintf(pe1.x * pinv); qp[5] = (int)rintf(pe1.y * pinv);
    qp[6] = (int)rintf(pe1.z * pinv); qp[7] = (int)rintf(pe1.w * pinv);
    const int plo = (qp[0] & 0xff) | ((qp[2] & 0xff) << 8)
                  | ((qp[4] & 0xff) << 16) | ((qp[6] & 0xff) << 24);
    const int phi = (qp[1] & 0xff) | ((qp[3] & 0xff) << 8)
                  | ((qp[5] & 0xff) << 16) | ((qp[7] & 0xff) << 24);
    const int m8psum = -8 * (qp[0] + qp[1] + qp[2] + qp[3]
                           + qp[4] + qp[5] + qp[6] + qp[7]);
    const uint M = 0x0F0F0F0Fu;

    float A0 = 0.f, A1 = 0.f, A2 = 0.f, A3 = 0.f;
    for (int clo = S; clo < E; clo += CHUNK) {
        const int chi = (clo + CHUNK < E) ? (clo + CHUNK) : E;
        // stage ids: coalesced, wave-uniform loop
        #pragma unroll
        for (int k = 0; k < CHUNK / 64; ++k) {
            const int idx = clo + lane + k * 64;
            if (idx < chi) lds_ids[w][lane + k * 64] = flat_papers[idx];
        }
        // FENCE: writes complete + compiler may not hoist reads above
        asm volatile("s_waitcnt lgkmcnt(0)" ::: "memory");
        __builtin_amdgcn_sched_barrier(0);

        int ge = (start > clo) ? start : clo;
        const int gend = (end < chi) ? end : chi;
        for (; ge + 4 <= gend; ge += 4) {
            const int li = ge - clo;
            const int p0 = lds_ids[w][li];
            const int p1 = lds_ids[w][li + 1];
            const int p2 = lds_ids[w][li + 2];
            const int p3 = lds_ids[w][li + 3];
            const uint u0 = imp_q4[((size_t)p0 << 3) + sub];
            const uint u1 = imp_q4[((size_t)p1 << 3) + sub];
            const uint u2 = imp_q4[((size_t)p2 << 3) + sub];
            const uint u3 = imp_q4[((size_t)p3 << 3) + sub];
            const float s0 = imp_scale[p0];
            const float s1 = imp_scale[p1];
            const float s2 = imp_scale[p2];
            const float s3 = imp_scale[p3];
            const int d0 = __builtin_amdgcn_sdot4((int)(u0 & M), plo,
                           __builtin_amdgcn_sdot4((int)((u0 >> 4) & M), phi, m8psum, false), false);
            const int d1 = __builtin_amdgcn_sdot4((int)(u1 & M), plo,
                           __builtin_amdgcn_sdot4((int)((u1 >> 4) & M), phi, m8psum, false), false);
            const int d2 = __builtin_amdgcn_sdot4((int)(u2 & M), plo,
                           __builtin_amdgcn_sdot4((int)((u2 >> 4) & M), phi, m8psum, false), false);
            const int d3 = __builtin_amdgcn_sdot4((int)(u3 & M), plo,
                           __builtin_amdgcn_sdot4((int)((u3 >> 4) & M), phi, m8psum, false), false);
            A0 = fmaf(s0, (float)d0, A0);
            A1 = fmaf(s1, (float)d1, A1);
            A2 = fmaf(s2, (float)d2, A2);
            A3 = fmaf(s3, (float)d3, A3);
        }
        for (; ge < gend; ++ge) {
            const int p = lds_ids[w][ge - clo];
            const uint u = imp_q4[((size_t)p << 3) + sub];
            const float s = imp_scale[p];
            const int d = __builtin_amdgcn_sdot4((int)(u & M), plo,
                          __builtin_amdgcn_sdot4((int)((u >> 4) & M), phi, m8psum, false), false);
            A0 = fmaf(s, (float)d, A0);
        }
        // FENCE: next chunk's staging writes may not sink above these reads
        __builtin_amdgcn_sched_barrier(0);
        asm volatile("" ::: "memory");
    }
    const float acc = sp * ((A0 + A1) + (A2 + A3));
#else
    const float pesum = pe0.x + pe0.y + pe0.z + pe0.w
                      + pe1.x + pe1.y + pe1.z + pe1.w;
    float A0 = 0.f, S0 = 0.f;
    for (int clo = S; clo < E; clo += CHUNK) {
        const int chi = (clo + CHUNK < E) ? (clo + CHUNK) : E;
        #pragma unroll
        for (int k = 0; k < CHUNK / 64; ++k) {
            const int idx = clo + lane + k * 64;
            if (idx < chi) lds_ids[w][lane + k * 64] = flat_papers[idx];
        }
        asm volatile("s_waitcnt lgkmcnt(0)" ::: "memory");
        __builtin_amdgcn_sched_barrier(0);
        int ge = (start > clo) ? start : clo;
        const int gend = (end < chi) ? end : chi;
        for (; ge < gend; ++ge) {
            const int p = lds_ids[w][ge - clo];
            const uint u = imp_q4[((size_t)p << 3) + sub];
            const float s = imp_scale[p];
            const uint lo = u & 0x0F0F0F0Fu, hi = (u >> 4) & 0x0F0F0F0Fu;
            const float d = (float)(lo & 0xffu)*pe0.x + (float)(hi & 0xffu)*pe0.y
                          + (float)((lo >> 8) & 0xffu)*pe0.z + (float)((hi >> 8) & 0xffu)*pe0.w
                          + (float)((lo >> 16) & 0xffu)*pe1.x + (float)((hi >> 16) & 0xffu)*pe1.y
                          + (float)(lo >> 24)*pe1.z + (float)(hi >> 24)*pe1.w;
            A0 = fmaf(s, d, A0);  S0 += s;
        }
        __builtin_amdgcn_sched_barrier(0);
        asm volatile("" ::: "memory");
    }
    const float acc = A0 - 8.0f * S0 * pesum;
#endif

    const int n = end - start;
    const float scale = (n > 0) ? rsqrtf((float)n) : 0.0f;
    float v = base + scale * acc;

    // reduce within the 8-lane group (all lanes reconverged here)
    v += __shfl_xor(v, 1, 64);
    v += __shfl_xor(v, 2, 64);
    v += __shfl_xor(v, 4, 64);

    if (sub == 0 && valid) {
        __builtin_nontemporal_store(v + sb + pb + 3.82f, out + (b0 + g));
    }
}

// ---------- f32 fallback (ws too small) ----------
__global__ __launch_bounds__(256) void svdpp_main_f32(
    const int*   __restrict__ scientist_ids,
    const int*   __restrict__ paper_ids,
    const int*   __restrict__ flat_papers,
    const int*   __restrict__ row_start,
    const float* __restrict__ scientist_factors,
    const float* __restrict__ paper_factors,
    const float* __restrict__ implicit_factors,
    const float* __restrict__ scientist_bias,
    const float* __restrict__ paper_bias,
    float*       __restrict__ out,
    int B) {
    const int wave = (int)((blockIdx.x * blockDim.x + threadIdx.x) >> 6);
    const int lane = threadIdx.x & 63;
    if (wave >= B) return;
    const int b   = wave;
    const int g   = lane >> 4;
    const int sub = lane & 15;

    const int start = row_start[b];
    const int end   = row_start[b + 1];
    const int n     = end - start;

    float4 accA = make_float4(0.f,0.f,0.f,0.f);
    int i = start;
    for (; i < end; i += 4) {
        const int e = i + g;
        if (e < end) {
            const int p = flat_papers[e];
            const float4 r = *reinterpret_cast<const float4*>(
                implicit_factors + ((size_t)p << 6) + (sub << 2));
            accA.x += r.x; accA.y += r.y; accA.z += r.z; accA.w += r.w;
        }
    }

    const float scale = (n > 0) ? rsqrtf((float)n) : 0.0f;
    const int sid = scientist_ids[b];
    const int pid = paper_ids[b];
    const float4 se = *reinterpret_cast<const float4*>(
        scientist_factors + ((size_t)sid << 6) + (sub << 2));
    const float4 pe = *reinterpret_cast<const float4*>(
        paper_factors + ((size_t)pid << 6) + (sub << 2));

    const float basedot = se.x*pe.x + se.y*pe.y + se.z*pe.z + se.w*pe.w;
    const float tdot    = accA.x*pe.x + accA.y*pe.y + accA.z*pe.z + accA.w*pe.w;
    float v = scale * tdot + ((g == 0) ? basedot : 0.0f);

    #pragma unroll
    for (int off = 1; off < 64; off <<= 1) v += __shfl_xor(v, off, 64);

    if (lane == 0) {
        out[b] = v + scientist_bias[sid] + paper_bias[pid] + 3.82f;
    }
}

extern "C" void kernel_launch(void* const* d_in, const int* in_sizes, int n_in,
                              void* d_out, int out_size, void* d_ws, size_t ws_size,
                              hipStream_t stream) {
    const int* scientist_ids       = (const int*)d_in[0];
    const int* paper_ids           = (const int*)d_in[1];
    const int* flat_papers         = (const int*)d_in[2];
    const int* segment_ids         = (const int*)d_in[3];
    const float* scientist_factors = (const float*)d_in[4];
    const float* paper_factors     = (const float*)d_in[5];
    const float* implicit_factors  = (const float*)d_in[6];
    const float* scientist_bias    = (const float*)d_in[7];
    const float* paper_bias        = (const float*)d_in[8];
    float* out = (float*)d_out;

    const int B      = in_sizes[0];
    const int T      = in_sizes[2];
    const int IMP_N  = in_sizes[6];          // NUM_PAPERS * EMB
    const int NROWS  = IMP_N / EMB;          // NUM_PAPERS

    auto align64 = [](size_t x) { return (x + 63) & ~(size_t)63; };
    size_t off0 = 0;                                   // row_start (B+1 ints)
    size_t off1 = align64(off0 + (size_t)(B + 1) * 4); // imp_q4  (NROWS*32B)
    size_t off2 = align64(off1 + (size_t)NROWS * 32);  // imp_scale (NROWS*4B)
    const size_t need = off2 + (size_t)NROWS * 4;

    int*   row_start  = (int*)((char*)d_ws + off0);
    uint*  imp_q4     = (uint*)((char*)d_ws + off1);
    float* imp_scale  = (float*)((char*)d_ws + off2);

    if (ws_size >= need) {
        {
            const int threads   = 256;
            const int segBlocks = (T + threads - 1) / threads;
            const int cvtBlocks = (NROWS + 31) / 32;   // 8 rows per wave
            prep_kernel<<<segBlocks + cvtBlocks, threads, 0, stream>>>(
                segment_ids, row_start, T, B,
                implicit_factors, imp_q4, imp_scale, NROWS, segBlocks);
        }
        {
            const int threads = 256;                   // 32 output rows per block
            const int blocks  = (B + 31) / 32;
            svdpp_main_q4<<<blocks, threads, 0, stream>>>(
                scientist_ids, paper_ids, flat_papers, row_start,
                scientist_factors, paper_factors, imp_q4, imp_scale,
                scientist_bias, paper_bias, out, B);
        }
    } else {
        {
            const int threads = 256;
            const int blocks  = (T + threads - 1) / threads;
            prep_kernel<<<blocks, threads, 0, stream>>>(
                segment_ids, row_start, T, B,
                implicit_factors, (uint*)nullptr, (float*)nullptr, 0, blocks);
        }
        const int threads = 256;
        const int blocks  = (B + 3) / 4;
        svdpp_main_f32<<<blocks, threads, 0, stream>>>(
            scientist_ids, paper_ids, flat_papers, row_start,
            scientist_factors, paper_factors, implicit_factors,
            scientist_bias, paper_bias, out, B);
    }
}